// Round 11
// baseline (477.890 us; speedup 1.0000x reference)
//
#include <hip/hip_runtime.h>
#include <hip/hip_bf16.h>

#define SQRT2C 1.41421356237309515f
#define LEAKF 0.2f

typedef __attribute__((ext_vector_type(4))) float f32x4;
typedef __attribute__((ext_vector_type(8))) __bf16 bf16x8;
typedef unsigned int u32x4 __attribute__((ext_vector_type(4)));
typedef unsigned int u32x2 __attribute__((ext_vector_type(2)));

#define GLOAD16(g, l) \
  __builtin_amdgcn_global_load_lds((const __attribute__((address_space(1))) void*)(const void*)(g), \
                                   (__attribute__((address_space(3))) void*)(void*)(l), 16, 0, 0)

__device__ __forceinline__ unsigned short f2bf(float f) {
  unsigned int u = __float_as_uint(f);
  unsigned int r = (u + 0x7fffu + ((u >> 16) & 1u)) >> 16;
  return (unsigned short)r;
}
__device__ __forceinline__ float bflo(unsigned int w) { return __uint_as_float(w << 16); }
__device__ __forceinline__ float bfhi(unsigned int w) { return __uint_as_float(w & 0xffff0000u); }

// blur 1-D factor: B1 = [1,3,3,1], zero outside.  Tm[rp][u][k] == B1v(4-2u-k+rp)  (verified r1-3)
constexpr float B1v(int c) { return (c < 0 || c > 3) ? 0.f : ((c == 0 || c == 3) ? 1.f : 3.f); }

// ---------------- s = w @ aff_w.T + aff_b + 1 ----------------
__global__ void k_affine(const float* __restrict__ w, const float* __restrict__ aw,
                         const float* __restrict__ ab, float* __restrict__ s, int C) {
  int wid = (blockIdx.x * blockDim.x + threadIdx.x) >> 6;
  int lane = threadIdx.x & 63;
  int b = wid / C, i = wid % C;
  const float* wr = w + (size_t)b * 512;
  const float* ar = aw + (size_t)i * 512;
  float acc = 0.f;
  #pragma unroll
  for (int l = 0; l < 512; l += 64) acc += wr[l + lane] * ar[l + lane];
  #pragma unroll
  for (int off = 32; off; off >>= 1) acc += __shfl_down(acc, off, 64);
  if (lane == 0) s[wid] = acc + ab[i] + 1.0f;
}

// ---------------- d[b,o] = rsqrt(sum_i s^2 * sum_tap w^2 + 1e-8) ----------------
__global__ void k_demod(const float* __restrict__ weight, const float* __restrict__ s,
                        float* __restrict__ d, int CIN) {
  int o = blockIdx.x & 255, b = blockIdx.x >> 8;
  int t = threadIdx.x;
  const float* wr = weight + (size_t)o * CIN * 9;
  const float* sr = s + (size_t)b * CIN;
  float acc = 0.f;
  for (int i = t; i < CIN; i += 256) {
    float sv = sr[i];
    float ws = 0.f;
    #pragma unroll
    for (int k = 0; k < 9; ++k) { float w = wr[(size_t)i * 9 + k]; ws += w * w; }
    acc += sv * sv * ws;
  }
  __shared__ float red[256];
  red[t] = acc; __syncthreads();
  for (int h = 128; h; h >>= 1) { if (t < h) red[t] += red[t + h]; __syncthreads(); }
  if (t == 0) d[blockIdx.x] = rsqrtf(red[0] + 1e-8f);
}

// ---- Wv[b][rp*3+kx][u][o][i] = sum_ky Tm[rp][u][ky] * wm1[ky][kx][o][i]  (vertical mix in weights)
__global__ void k_wvert(const float* __restrict__ w1, const float* __restrict__ s1,
                        const float* __restrict__ d1, unsigned short* __restrict__ Wv) {
  int t = blockIdx.x * 256 + threadIdx.x;   // 8*256*512 threads
  int i = t & 511, o = (t >> 9) & 255, b = t >> 17;
  float sd = s1[b * 512 + i] * d1[b * 256 + o];
  const float* wp = w1 + ((size_t)o * 512 + i) * 9;
  float wm[3][3];
  #pragma unroll
  for (int ky = 0; ky < 3; ++ky)
    #pragma unroll
    for (int kx = 0; kx < 3; ++kx) wm[ky][kx] = wp[ky * 3 + kx] * sd;
  #pragma unroll
  for (int rp = 0; rp < 2; ++rp)
    #pragma unroll
    for (int u = 0; u < 3; ++u)
      #pragma unroll
      for (int kx = 0; kx < 3; ++kx) {
        float v = 0.f;
        #pragma unroll
        for (int ky = 0; ky < 3; ++ky) v += B1v(4 - 2 * u - ky + rp) * wm[ky][kx];
        Wv[(((size_t)(b * 6 + rp * 3 + kx)) * 3 + u) * 131072 + (size_t)o * 512 + i] = f2bf(v);
      }
}

// ---------------- W2m[b][tap][o][i] (bf16) ----------------
__global__ void k_weff2(const float* __restrict__ w2, const float* __restrict__ s2,
                        const float* __restrict__ d2, unsigned short* __restrict__ Wm) {
  int t = blockIdx.x * 256 + threadIdx.x;   // 8*256*256 threads
  int i = t & 255, o = (t >> 8) & 255, b = t >> 16;
  float sd = s2[b * 256 + i] * d2[b * 256 + o];
  const float* wp = w2 + ((size_t)o * 256 + i) * 9;
  #pragma unroll
  for (int k = 0; k < 9; ++k)
    Wm[((size_t)(b * 9 + k) * 256 + o) * 256 + i] = f2bf(wp[k] * sd);
}

// ---------------- border-only zero fill for y1p halo ----------------
__global__ void k_border_y1(unsigned short* __restrict__ y1p) {
  int t = blockIdx.x * 256 + threadIdx.x;   // 8*516*32 threads, 1 uint4 each
  int l = t & 31;
  int c = (t >> 5) % 516;
  int b = (t >> 5) / 516;
  int p_, q_;
  if (c < 130)      { p_ = 0;       q_ = c; }
  else if (c < 260) { p_ = 129;     q_ = c - 130; }
  else if (c < 388) { p_ = c - 259; q_ = 0; }
  else              { p_ = c - 387; q_ = 129; }
  uint4* p = (uint4*)(y1p + (((size_t)(b * 130) + p_) * 130 + q_) * 256);
  p[l] = make_uint4(0u, 0u, 0u, 0u);
}

// ---------------- zero rows 0 and 65 of xt_v [8][66][64][512] ----------------
__global__ void k_fillv(unsigned short* __restrict__ xt) {
  int t = blockIdx.x * 256 + threadIdx.x;   // 65536 uint4
  int j = t & 4095;
  int r = (t >> 12) & 1;
  int b = t >> 13;
  uint4* p = (uint4*)(xt + ((size_t)(b * 66) + (r ? 65 : 0)) * 64 * 512);
  p[j] = make_uint4(0u, 0u, 0u, 0u);
}

// ---- x [8][512][64][64] f32 -> xt_v [8][66][64][512] bf16 (rows 1..64 = x rows 0..63) ----
__global__ void k_txpose(const float* __restrict__ x, unsigned short* __restrict__ xt) {
  int bid = blockIdx.x;            // 8192 = b(8) * y(64) * x0(2) * i0(8)
  int i0 = (bid & 7) * 64;
  int x0 = ((bid >> 3) & 1) * 32;
  int y  = (bid >> 4) & 63;
  int b  = bid >> 10;
  int tx = threadIdx.x & 31, ty = threadIdx.x >> 5;
  __shared__ float tile[64][33];
  const float* xp = x + ((size_t)(b * 512 + i0) * 64 + y) * 64 + x0;
  for (int ii = ty; ii < 64; ii += 8) tile[ii][tx] = xp[(size_t)ii * 4096 + tx];
  __syncthreads();
  unsigned short* op = xt + (((size_t)(b * 66) + y + 1) * 64 + x0) * 512 + i0;
  for (int xx = ty; xx < 32; xx += 8) {
    int iL = tx * 2;
    unsigned int pk = (unsigned int)f2bf(tile[iL][xx]) | ((unsigned int)f2bf(tile[iL + 1][xx]) << 16);
    *(unsigned int*)&op[(size_t)xx * 512 + iL] = pk;
  }
}

// ================= 256x256-tile, 8-wave, BK=32, 4-deep ring, ONE barrier per K-tile =================
// OM=3: vertical-tap A-GEMM (TAPS=3, row stride GRID); A written with NONTEMPORAL stores so the
//       100 MB streaming intermediate never displaces y1p in the Infinity Cache (read once by hmix).
// OM=2: conv2 3x3 on halo grid, f32 output (nontemporal) with noise/bias/lrelu.
template<int CIN, int GSH, int HP, int RHO_N, int TAPS, int PANB, int OM>
__global__ __launch_bounds__(512, 2) void k_conv8(
    const unsigned short* __restrict__ Xt,
    const unsigned short* __restrict__ Wt,
    const float* __restrict__ noise,
    const float* __restrict__ nsp,
    const float* __restrict__ bias,
    unsigned short* __restrict__ Yb,
    float* __restrict__ Yf)
{
  constexpr int GRID = 1 << GSH;
  constexpr int NT = (GRID * GRID) / 256;
  constexpr int NKT = TAPS * (CIN / 32);
  constexpr int KMASK = (CIN / 32) - 1;
  constexpr int KSH = (CIN == 512) ? 4 : 3;
  constexpr int TOT = NT * RHO_N * 8;
  constexpr int ROWW = (OM == 3) ? GRID : HP;   // pixel-row width of Xt
  extern __shared__ char smem[];

  int bid0 = blockIdx.x;
  int bid = (bid0 & 7) * (TOT / 8) + (bid0 >> 3);   // XCD-chunked, bijective (TOT%8==0)
  int nt = bid % NT;
  int rho = (bid / NT) % RHO_N;
  int b = bid / (NT * RHO_N);
  int pix0 = nt * 256;
  int tid = threadIdx.x, lane = tid & 63, w = tid >> 6;
  int lr = lane & 15, lq = lane >> 4;
  int wr = w >> 2, wc = w & 3;

  // ---- staging lane geometry (inverse swizzle on global source) ----
  int p_ = lane & 7;
  int l8 = lane >> 3;
  int s0 = p_ ^ l8;
  int hs = s0 >> 2;
  int koffs = (s0 & 3) * 8;
  int rowA0 = 32 * w + 2 * l8 + hs;
  const unsigned short* Wp = Wt + ((size_t)b * PANB + rho * TAPS) * 256 * CIN;
  int aLane0 = rowA0 * CIN + koffs;
  int px0 = pix0 + 32 * w + 2 * l8 + hs;
  int gy0 = px0 >> GSH,        gx0 = px0 & (GRID - 1);
  int gy1 = (px0 + 16) >> GSH, gx1 = (px0 + 16) & (GRID - 1);
  const unsigned short* pB0 = Xt + (((size_t)b * HP + gy0) * ROWW + gx0) * CIN + koffs;
  const unsigned short* pB1 = Xt + (((size_t)b * HP + gy1) * ROWW + gx1) * CIN + koffs;
  int dstA = w * 2048;
  int dstB = 16384 + w * 2048;

  // ---- fragment-read lane geometry (swizzled ds_read addresses) ----
  int xorterm = (((lr & 1) << 6) | (lq << 4)) ^ (((lr >> 1) & 7) << 4);
  int ldsAr = (wr * 64 + (lr >> 1)) * 128 + xorterm;
  int ldsBr = 16384 + (wc * 32 + (lr >> 1)) * 128 + xorterm;

  // ---- prologue: stage K-tiles 0 and 1 (tap 0) ----
  #pragma unroll
  for (int kt = 0; kt < 2; ++kt) {
    int ko = kt << 5;
    const unsigned short* sa = Wp + ko + aLane0;
    char* da = smem + (kt << 15) + dstA;
    GLOAD16(sa, da);
    GLOAD16(sa + 16 * CIN, da + 1024);
    char* db = smem + (kt << 15) + dstB;
    GLOAD16(pB0 + ko, db);
    GLOAD16(pB1 + ko, db + 1024);
  }
  asm volatile("s_waitcnt vmcnt(4)" ::: "memory");
  __builtin_amdgcn_s_barrier();

  f32x4 acc[8][4];
  #pragma unroll
  for (int m = 0; m < 8; ++m)
    #pragma unroll
    for (int n = 0; n < 4; ++n) acc[m][n] = (f32x4){0.f, 0.f, 0.f, 0.f};

  #pragma unroll 1
  for (int t = 0; t < NKT; ++t) {
    const char* Ab = smem + ((t & 3) << 15);
    bf16x8 bv[4], af[4];

    // ---- stage K-tile t+2 (all 4 loads up front; they stay in flight across the barrier) ----
    if (t + 2 < NKT) {
      int k2 = t + 2;
      int tap2 = k2 >> KSH, ko2 = (k2 & KMASK) << 5;
      const unsigned short* sa = Wp + (size_t)tap2 * (256 * CIN) + ko2 + aLane0;
      char* da = smem + ((k2 & 3) << 15) + dstA;
      GLOAD16(sa, da);
      GLOAD16(sa + 16 * CIN, da + 1024);
      size_t toff2 = (OM == 3) ? ((size_t)tap2 * GRID * CIN)
                               : (((size_t)(tap2 / 3) * HP + (tap2 % 3)) * CIN);
      char* db = smem + ((k2 & 3) << 15) + dstB;
      GLOAD16(pB0 + toff2 + ko2, db);
      GLOAD16(pB1 + toff2 + ko2, db + 1024);
    }

    // ---- compute tile t (compiler-counted lgkmcnt overlaps ds_read with MFMA) ----
    #pragma unroll
    for (int n = 0; n < 4; ++n) bv[n] = *(const bf16x8*)(Ab + ldsBr + n * 1024);
    #pragma unroll
    for (int m = 0; m < 4; ++m) af[m] = *(const bf16x8*)(Ab + ldsAr + m * 1024);
    __builtin_amdgcn_s_setprio(1);
    #pragma unroll
    for (int m = 0; m < 4; ++m)
      #pragma unroll
      for (int n = 0; n < 4; ++n)
        acc[m][n] = __builtin_amdgcn_mfma_f32_16x16x32_bf16(af[m], bv[n], acc[m][n], 0, 0, 0);
    __builtin_amdgcn_s_setprio(0);
    #pragma unroll
    for (int m = 0; m < 4; ++m) af[m] = *(const bf16x8*)(Ab + ldsAr + (m + 4) * 1024);
    __builtin_amdgcn_s_setprio(1);
    #pragma unroll
    for (int m = 0; m < 4; ++m)
      #pragma unroll
      for (int n = 0; n < 4; ++n)
        acc[m + 4][n] = __builtin_amdgcn_mfma_f32_16x16x32_bf16(af[m], bv[n], acc[m + 4][n], 0, 0, 0);
    __builtin_amdgcn_s_setprio(0);

    // ---- single end-of-tile sync: make t+1 resident, keep t+2 in flight ----
    if (t + 2 < NKT)      { asm volatile("s_waitcnt vmcnt(4)" ::: "memory"); }
    else if (t + 1 < NKT) { asm volatile("s_waitcnt vmcnt(0)" ::: "memory"); }
    __builtin_amdgcn_s_barrier();
  }

  // ---- epilogue ----
  if constexpr (OM == 2) {
    float ns = nsp[0];
    #pragma unroll
    for (int m = 0; m < 8; ++m) {
      int o = wr * 128 + m * 16 + lq * 4;
      #pragma unroll
      for (int n = 0; n < 4; ++n) {
        int pix = pix0 + wc * 64 + n * 16 + lr;
        int p = pix >> 7, q = pix & 127;
        float nz = ns * noise[((size_t)b << 14) + (p << 7) + q];
        #pragma unroll
        for (int r = 0; r < 4; ++r) {
          float v = acc[m][n][r] + nz + bias[o + r];
          v = (v >= 0.f ? v : LEAKF * v) * SQRT2C;
          __builtin_nontemporal_store(v, &Yf[(((size_t)b * 256 + o + r) << 14) + (p << 7) + q]);
        }
      }
    }
  } else {
    // OM==3: A[b][kx][p=2gy+rp][gx][o] bf16, rho = rp*3+kx — NONTEMPORAL (streaming, read-once)
    int rp = rho / 3, kx = rho % 3;
    #pragma unroll
    for (int m = 0; m < 8; ++m) {
      int o = wr * 128 + m * 16 + lq * 4;
      #pragma unroll
      for (int n = 0; n < 4; ++n) {
        int pix = pix0 + wc * 64 + n * 16 + lr;
        int p2 = ((pix >> 6) << 1) + rp, gxp = pix & 63;
        u32x2 pk;
        pk[0] = (unsigned)f2bf(acc[m][n][0]) | ((unsigned)f2bf(acc[m][n][1]) << 16);
        pk[1] = (unsigned)f2bf(acc[m][n][2]) | ((unsigned)f2bf(acc[m][n][3]) << 16);
        __builtin_nontemporal_store(pk,
            (u32x2*)&Yb[((((size_t)(b * 3) + kx) * 128 + p2) * 64 + gxp) * 256 + o]);
      }
    }
  }
}

// ---------------- horizontal mix + epilogue: y1p interior (A read nontemporally) ----------------
__global__ void k_hmix(const unsigned short* __restrict__ A, const float* __restrict__ noise,
                       const float* __restrict__ nsp, const float* __restrict__ bias,
                       unsigned short* __restrict__ y1p) {
  int bid = blockIdx.x;                  // 16384 = b(8)*p(128)*qg(16)
  int qg = bid & 15;
  int p = (bid >> 4) & 127;
  int b = bid >> 11;
  int o0 = (threadIdx.x & 31) * 8;
  int q = qg * 8 + (threadIdx.x >> 5);
  int gq = q >> 1;
  float rqf = (float)(q & 1);
  float acc[8];
  #pragma unroll
  for (int r = 0; r < 8; ++r) acc[r] = 0.f;
  #pragma unroll
  for (int v = 0; v < 3; ++v) {
    int gxx = gq + v - 1;
    float bmask = (gxx >= 0 && gxx <= 63) ? 1.f : 0.f;
    int gxc = gxx < 0 ? 0 : (gxx > 63 ? 63 : gxx);
    #pragma unroll
    for (int kx = 0; kx < 3; ++kx) {
      float C0 = B1v(4 - 2 * v - kx);
      float C1 = B1v(5 - 2 * v - kx);
      if (C0 == 0.f && C1 == 0.f) continue;            // folds at compile time
      float coef = (C0 + (C1 - C0) * rqf) * bmask;
      u32x4 av = __builtin_nontemporal_load(
          (const u32x4*)&A[(((size_t)(b * 3 + kx) * 128 + p) * 64 + gxc) * 256 + o0]);
      acc[0] += coef * bflo(av[0]); acc[1] += coef * bfhi(av[0]);
      acc[2] += coef * bflo(av[1]); acc[3] += coef * bfhi(av[1]);
      acc[4] += coef * bflo(av[2]); acc[5] += coef * bfhi(av[2]);
      acc[6] += coef * bflo(av[3]); acc[7] += coef * bfhi(av[3]);
    }
  }
  float ns = nsp[0];
  float nz = ns * noise[((size_t)b << 14) + (p << 7) + q];
  float4 bl = *(const float4*)&bias[o0];
  float4 bh = *(const float4*)&bias[o0 + 4];
  float bb[8] = {bl.x, bl.y, bl.z, bl.w, bh.x, bh.y, bh.z, bh.w};
  unsigned short ov[8];
  #pragma unroll
  for (int r = 0; r < 8; ++r) {
    float vv = acc[r] * 0.0625f + nz + bb[r];
    vv = (vv >= 0.f ? vv : LEAKF * vv) * SQRT2C;
    ov[r] = f2bf(vv);
  }
  uint4 pk;
  pk.x = (unsigned)ov[0] | ((unsigned)ov[1] << 16);
  pk.y = (unsigned)ov[2] | ((unsigned)ov[3] << 16);
  pk.z = (unsigned)ov[4] | ((unsigned)ov[5] << 16);
  pk.w = (unsigned)ov[6] | ((unsigned)ov[7] << 16);
  *(uint4*)&y1p[(((size_t)(b * 130) + p + 1) * 130 + q + 1) * 256 + o0] = pk;
}

extern "C" void kernel_launch(void* const* d_in, const int* in_sizes, int n_in,
                              void* d_out, int out_size, void* d_ws, size_t ws_size,
                              hipStream_t stream) {
  (void)in_sizes; (void)n_in; (void)out_size; (void)ws_size;
  const float* x       = (const float*)d_in[0];
  const float* w1      = (const float*)d_in[1];
  const float* w2      = (const float*)d_in[2];
  const float* noise1  = (const float*)d_in[3];
  const float* noise2  = (const float*)d_in[4];
  const float* weight1 = (const float*)d_in[5];
  const float* aff1w   = (const float*)d_in[6];
  const float* aff1b   = (const float*)d_in[7];
  const float* weight2 = (const float*)d_in[8];
  const float* aff2w   = (const float*)d_in[9];
  const float* aff2b   = (const float*)d_in[10];
  const float* ns1     = (const float*)d_in[11];
  const float* ns2     = (const float*)d_in[12];
  const float* b1      = (const float*)d_in[13];
  const float* b2      = (const float*)d_in[14];

  // Workspace map (proven-safe bound: <= 189,882,368 B):
  //   header           0 ..      40,960
  //   xt_v        40,960 ..  34,643,968   (8*66*64*512 bf16)
  //   Wv      34,643,968 ..  72,392,704   (8*6*3*256*512 bf16)
  //   W2m     72,392,704 ..  81,829,888
  //   A       81,829,888 .. 182,493,184   (8*3*128*64*256 bf16 = 100,663,296)
  //   y1p         40,960 ..  69,263,360   (aliases xt_v+Wv, both dead before hmix)
  char* ws = (char*)d_ws;
  float* s1 = (float*)(ws + 0);
  float* s2 = (float*)(ws + 16384);
  float* d1 = (float*)(ws + 24576);
  float* d2 = (float*)(ws + 32768);
  unsigned short* xt   = (unsigned short*)(ws + 40960);
  unsigned short* Wv   = (unsigned short*)(ws + 34643968);
  unsigned short* W2m  = (unsigned short*)(ws + 72392704);
  unsigned short* A    = (unsigned short*)(ws + 81829888);
  unsigned short* y1p  = (unsigned short*)(ws + 40960);

  (void)hipFuncSetAttribute((const void*)k_conv8<512, 6, 66, 6, 3, 18, 3>,
                            hipFuncAttributeMaxDynamicSharedMemorySize, 131072);
  (void)hipFuncSetAttribute((const void*)k_conv8<256, 7, 130, 1, 9, 9, 2>,
                            hipFuncAttributeMaxDynamicSharedMemorySize, 131072);

  k_affine<<<1024, 256, 0, stream>>>(w1, aff1w, aff1b, s1, 512);
  k_affine<<<512,  256, 0, stream>>>(w2, aff2w, aff2b, s2, 256);
  k_demod<<<2048, 256, 0, stream>>>(weight1, s1, d1, 512);
  k_demod<<<2048, 256, 0, stream>>>(weight2, s2, d2, 256);
  k_wvert<<<4096, 256, 0, stream>>>(weight1, s1, d1, Wv);
  k_weff2<<<2048, 256, 0, stream>>>(weight2, s2, d2, W2m);
  k_fillv<<<256, 256, 0, stream>>>(xt);
  k_txpose<<<8192, 256, 0, stream>>>(x, xt);

  // A-GEMM: vertical taps folded into weights; 6 panels (rp,kx) per b, K=1536.
  k_conv8<512, 6, 66, 6, 3, 18, 3><<<768, 512, 131072, stream>>>(
      xt, Wv, nullptr, nullptr, nullptr, A, nullptr);

  k_border_y1<<<516, 256, 0, stream>>>(y1p);
  k_hmix<<<16384, 256, 0, stream>>>(A, noise1, ns1, b1, y1p);
  k_conv8<256, 7, 130, 1, 9, 9, 2><<<512, 512, 131072, stream>>>(
      y1p, W2m, noise2, ns2, b2, nullptr, (float*)d_out);
}

// Round 12
// 477.852 us; speedup vs baseline: 1.0001x; 1.0001x over previous
//
#include <hip/hip_runtime.h>
#include <hip/hip_bf16.h>

#define SQRT2C 1.41421356237309515f
#define LEAKF 0.2f

typedef __attribute__((ext_vector_type(4))) float f32x4;
typedef __attribute__((ext_vector_type(8))) __bf16 bf16x8;
typedef unsigned int u32x4 __attribute__((ext_vector_type(4)));
typedef unsigned int u32x2 __attribute__((ext_vector_type(2)));

#define GLOAD16(g, l) \
  __builtin_amdgcn_global_load_lds((const __attribute__((address_space(1))) void*)(const void*)(g), \
                                   (__attribute__((address_space(3))) void*)(void*)(l), 16, 0, 0)

__device__ __forceinline__ unsigned short f2bf(float f) {
  unsigned int u = __float_as_uint(f);
  unsigned int r = (u + 0x7fffu + ((u >> 16) & 1u)) >> 16;
  return (unsigned short)r;
}
__device__ __forceinline__ float bflo(unsigned int w) { return __uint_as_float(w << 16); }
__device__ __forceinline__ float bfhi(unsigned int w) { return __uint_as_float(w & 0xffff0000u); }

// blur 1-D factor: B1 = [1,3,3,1], zero outside.  Tm[rp][u][k] == B1v(4-2u-k+rp)  (verified r1-3)
constexpr float B1v(int c) { return (c < 0 || c > 3) ? 0.f : ((c == 0 || c == 3) ? 1.f : 3.f); }

// ---------------- s = w @ aff_w.T + aff_b + 1 ----------------
__global__ void k_affine(const float* __restrict__ w, const float* __restrict__ aw,
                         const float* __restrict__ ab, float* __restrict__ s, int C) {
  int wid = (blockIdx.x * blockDim.x + threadIdx.x) >> 6;
  int lane = threadIdx.x & 63;
  int b = wid / C, i = wid % C;
  const float* wr = w + (size_t)b * 512;
  const float* ar = aw + (size_t)i * 512;
  float acc = 0.f;
  #pragma unroll
  for (int l = 0; l < 512; l += 64) acc += wr[l + lane] * ar[l + lane];
  #pragma unroll
  for (int off = 32; off; off >>= 1) acc += __shfl_down(acc, off, 64);
  if (lane == 0) s[wid] = acc + ab[i] + 1.0f;
}

// ---------------- d[b,o] = rsqrt(sum_i s^2 * sum_tap w^2 + 1e-8) ----------------
__global__ void k_demod(const float* __restrict__ weight, const float* __restrict__ s,
                        float* __restrict__ d, int CIN) {
  int o = blockIdx.x & 255, b = blockIdx.x >> 8;
  int t = threadIdx.x;
  const float* wr = weight + (size_t)o * CIN * 9;
  const float* sr = s + (size_t)b * CIN;
  float acc = 0.f;
  for (int i = t; i < CIN; i += 256) {
    float sv = sr[i];
    float ws = 0.f;
    #pragma unroll
    for (int k = 0; k < 9; ++k) { float w = wr[(size_t)i * 9 + k]; ws += w * w; }
    acc += sv * sv * ws;
  }
  __shared__ float red[256];
  red[t] = acc; __syncthreads();
  for (int h = 128; h; h >>= 1) { if (t < h) red[t] += red[t + h]; __syncthreads(); }
  if (t == 0) d[blockIdx.x] = rsqrtf(red[0] + 1e-8f);
}

// ---- Wv[b][rp*3+kx][u][o][i] = sum_ky Tm[rp][u][ky] * wm1[ky][kx][o][i]  (vertical mix in weights)
__global__ void k_wvert(const float* __restrict__ w1, const float* __restrict__ s1,
                        const float* __restrict__ d1, unsigned short* __restrict__ Wv) {
  int t = blockIdx.x * 256 + threadIdx.x;   // 8*256*512 threads
  int i = t & 511, o = (t >> 9) & 255, b = t >> 17;
  float sd = s1[b * 512 + i] * d1[b * 256 + o];
  const float* wp = w1 + ((size_t)o * 512 + i) * 9;
  float wm[3][3];
  #pragma unroll
  for (int ky = 0; ky < 3; ++ky)
    #pragma unroll
    for (int kx = 0; kx < 3; ++kx) wm[ky][kx] = wp[ky * 3 + kx] * sd;
  #pragma unroll
  for (int rp = 0; rp < 2; ++rp)
    #pragma unroll
    for (int u = 0; u < 3; ++u)
      #pragma unroll
      for (int kx = 0; kx < 3; ++kx) {
        float v = 0.f;
        #pragma unroll
        for (int ky = 0; ky < 3; ++ky) v += B1v(4 - 2 * u - ky + rp) * wm[ky][kx];
        Wv[(((size_t)(b * 6 + rp * 3 + kx)) * 3 + u) * 131072 + (size_t)o * 512 + i] = f2bf(v);
      }
}

// ---------------- W2m[b][tap][o][i] (bf16) ----------------
__global__ void k_weff2(const float* __restrict__ w2, const float* __restrict__ s2,
                        const float* __restrict__ d2, unsigned short* __restrict__ Wm) {
  int t = blockIdx.x * 256 + threadIdx.x;   // 8*256*256 threads
  int i = t & 255, o = (t >> 8) & 255, b = t >> 16;
  float sd = s2[b * 256 + i] * d2[b * 256 + o];
  const float* wp = w2 + ((size_t)o * 256 + i) * 9;
  #pragma unroll
  for (int k = 0; k < 9; ++k)
    Wm[((size_t)(b * 9 + k) * 256 + o) * 256 + i] = f2bf(wp[k] * sd);
}

// ---------------- border-only zero fill for y1p halo ----------------
__global__ void k_border_y1(unsigned short* __restrict__ y1p) {
  int t = blockIdx.x * 256 + threadIdx.x;   // 8*516*32 threads, 1 uint4 each
  int l = t & 31;
  int c = (t >> 5) % 516;
  int b = (t >> 5) / 516;
  int p_, q_;
  if (c < 130)      { p_ = 0;       q_ = c; }
  else if (c < 260) { p_ = 129;     q_ = c - 130; }
  else if (c < 388) { p_ = c - 259; q_ = 0; }
  else              { p_ = c - 387; q_ = 129; }
  uint4* p = (uint4*)(y1p + (((size_t)(b * 130) + p_) * 130 + q_) * 256);
  p[l] = make_uint4(0u, 0u, 0u, 0u);
}

// ---------------- zero rows 0 and 65 of xt_v [8][66][64][512] ----------------
__global__ void k_fillv(unsigned short* __restrict__ xt) {
  int t = blockIdx.x * 256 + threadIdx.x;   // 65536 uint4
  int j = t & 4095;
  int r = (t >> 12) & 1;
  int b = t >> 13;
  uint4* p = (uint4*)(xt + ((size_t)(b * 66) + (r ? 65 : 0)) * 64 * 512);
  p[j] = make_uint4(0u, 0u, 0u, 0u);
}

// ---- x [8][512][64][64] f32 -> xt_v [8][66][64][512] bf16 (rows 1..64 = x rows 0..63) ----
__global__ void k_txpose(const float* __restrict__ x, unsigned short* __restrict__ xt) {
  int bid = blockIdx.x;            // 8192 = b(8) * y(64) * x0(2) * i0(8)
  int i0 = (bid & 7) * 64;
  int x0 = ((bid >> 3) & 1) * 32;
  int y  = (bid >> 4) & 63;
  int b  = bid >> 10;
  int tx = threadIdx.x & 31, ty = threadIdx.x >> 5;
  __shared__ float tile[64][33];
  const float* xp = x + ((size_t)(b * 512 + i0) * 64 + y) * 64 + x0;
  for (int ii = ty; ii < 64; ii += 8) tile[ii][tx] = xp[(size_t)ii * 4096 + tx];
  __syncthreads();
  unsigned short* op = xt + (((size_t)(b * 66) + y + 1) * 64 + x0) * 512 + i0;
  for (int xx = ty; xx < 32; xx += 8) {
    int iL = tx * 2;
    unsigned int pk = (unsigned int)f2bf(tile[iL][xx]) | ((unsigned int)f2bf(tile[iL + 1][xx]) << 16);
    *(unsigned int*)&op[(size_t)xx * 512 + iL] = pk;
  }
}

// ================= 256x256-tile, 8-wave, BK=32, 4-deep ring, ONE barrier per K-tile =================
// OM=3: vertical-tap A-GEMM (TAPS=3, row stride GRID); A written with NONTEMPORAL stores so the
//       100 MB streaming intermediate never displaces y1p in the Infinity Cache (read once by hmix).
// OM=2: conv2 3x3 on halo grid, f32 output (nontemporal) with noise/bias/lrelu.
template<int CIN, int GSH, int HP, int RHO_N, int TAPS, int PANB, int OM>
__global__ __launch_bounds__(512, 2) void k_conv8(
    const unsigned short* __restrict__ Xt,
    const unsigned short* __restrict__ Wt,
    const float* __restrict__ noise,
    const float* __restrict__ nsp,
    const float* __restrict__ bias,
    unsigned short* __restrict__ Yb,
    float* __restrict__ Yf)
{
  constexpr int GRID = 1 << GSH;
  constexpr int NT = (GRID * GRID) / 256;
  constexpr int NKT = TAPS * (CIN / 32);
  constexpr int KMASK = (CIN / 32) - 1;
  constexpr int KSH = (CIN == 512) ? 4 : 3;
  constexpr int TOT = NT * RHO_N * 8;
  constexpr int ROWW = (OM == 3) ? GRID : HP;   // pixel-row width of Xt
  extern __shared__ char smem[];

  int bid0 = blockIdx.x;
  int bid = (bid0 & 7) * (TOT / 8) + (bid0 >> 3);   // XCD-chunked, bijective (TOT%8==0)
  int nt = bid % NT;
  int rho = (bid / NT) % RHO_N;
  int b = bid / (NT * RHO_N);
  int pix0 = nt * 256;
  int tid = threadIdx.x, lane = tid & 63, w = tid >> 6;
  int lr = lane & 15, lq = lane >> 4;
  int wr = w >> 2, wc = w & 3;

  // ---- staging lane geometry (inverse swizzle on global source) ----
  int p_ = lane & 7;
  int l8 = lane >> 3;
  int s0 = p_ ^ l8;
  int hs = s0 >> 2;
  int koffs = (s0 & 3) * 8;
  int rowA0 = 32 * w + 2 * l8 + hs;
  const unsigned short* Wp = Wt + ((size_t)b * PANB + rho * TAPS) * 256 * CIN;
  int aLane0 = rowA0 * CIN + koffs;
  int px0 = pix0 + 32 * w + 2 * l8 + hs;
  int gy0 = px0 >> GSH,        gx0 = px0 & (GRID - 1);
  int gy1 = (px0 + 16) >> GSH, gx1 = (px0 + 16) & (GRID - 1);
  const unsigned short* pB0 = Xt + (((size_t)b * HP + gy0) * ROWW + gx0) * CIN + koffs;
  const unsigned short* pB1 = Xt + (((size_t)b * HP + gy1) * ROWW + gx1) * CIN + koffs;
  int dstA = w * 2048;
  int dstB = 16384 + w * 2048;

  // ---- fragment-read lane geometry (swizzled ds_read addresses) ----
  int xorterm = (((lr & 1) << 6) | (lq << 4)) ^ (((lr >> 1) & 7) << 4);
  int ldsAr = (wr * 64 + (lr >> 1)) * 128 + xorterm;
  int ldsBr = 16384 + (wc * 32 + (lr >> 1)) * 128 + xorterm;

  // ---- prologue: stage K-tiles 0 and 1 (tap 0) ----
  #pragma unroll
  for (int kt = 0; kt < 2; ++kt) {
    int ko = kt << 5;
    const unsigned short* sa = Wp + ko + aLane0;
    char* da = smem + (kt << 15) + dstA;
    GLOAD16(sa, da);
    GLOAD16(sa + 16 * CIN, da + 1024);
    char* db = smem + (kt << 15) + dstB;
    GLOAD16(pB0 + ko, db);
    GLOAD16(pB1 + ko, db + 1024);
  }
  asm volatile("s_waitcnt vmcnt(4)" ::: "memory");
  __builtin_amdgcn_s_barrier();

  f32x4 acc[8][4];
  #pragma unroll
  for (int m = 0; m < 8; ++m)
    #pragma unroll
    for (int n = 0; n < 4; ++n) acc[m][n] = (f32x4){0.f, 0.f, 0.f, 0.f};

  #pragma unroll 1
  for (int t = 0; t < NKT; ++t) {
    const char* Ab = smem + ((t & 3) << 15);
    bf16x8 bv[4], af[4];

    // ---- stage K-tile t+2 (all 4 loads up front; they stay in flight across the barrier) ----
    if (t + 2 < NKT) {
      int k2 = t + 2;
      int tap2 = k2 >> KSH, ko2 = (k2 & KMASK) << 5;
      const unsigned short* sa = Wp + (size_t)tap2 * (256 * CIN) + ko2 + aLane0;
      char* da = smem + ((k2 & 3) << 15) + dstA;
      GLOAD16(sa, da);
      GLOAD16(sa + 16 * CIN, da + 1024);
      size_t toff2 = (OM == 3) ? ((size_t)tap2 * GRID * CIN)
                               : (((size_t)(tap2 / 3) * HP + (tap2 % 3)) * CIN);
      char* db = smem + ((k2 & 3) << 15) + dstB;
      GLOAD16(pB0 + toff2 + ko2, db);
      GLOAD16(pB1 + toff2 + ko2, db + 1024);
    }

    // ---- compute tile t (compiler-counted lgkmcnt overlaps ds_read with MFMA) ----
    #pragma unroll
    for (int n = 0; n < 4; ++n) bv[n] = *(const bf16x8*)(Ab + ldsBr + n * 1024);
    #pragma unroll
    for (int m = 0; m < 4; ++m) af[m] = *(const bf16x8*)(Ab + ldsAr + m * 1024);
    __builtin_amdgcn_s_setprio(1);
    #pragma unroll
    for (int m = 0; m < 4; ++m)
      #pragma unroll
      for (int n = 0; n < 4; ++n)
        acc[m][n] = __builtin_amdgcn_mfma_f32_16x16x32_bf16(af[m], bv[n], acc[m][n], 0, 0, 0);
    __builtin_amdgcn_s_setprio(0);
    #pragma unroll
    for (int m = 0; m < 4; ++m) af[m] = *(const bf16x8*)(Ab + ldsAr + (m + 4) * 1024);
    __builtin_amdgcn_s_setprio(1);
    #pragma unroll
    for (int m = 0; m < 4; ++m)
      #pragma unroll
      for (int n = 0; n < 4; ++n)
        acc[m + 4][n] = __builtin_amdgcn_mfma_f32_16x16x32_bf16(af[m], bv[n], acc[m + 4][n], 0, 0, 0);
    __builtin_amdgcn_s_setprio(0);

    // ---- single end-of-tile sync: make t+1 resident, keep t+2 in flight ----
    if (t + 2 < NKT)      { asm volatile("s_waitcnt vmcnt(4)" ::: "memory"); }
    else if (t + 1 < NKT) { asm volatile("s_waitcnt vmcnt(0)" ::: "memory"); }
    __builtin_amdgcn_s_barrier();
  }

  // ---- epilogue ----
  if constexpr (OM == 2) {
    float ns = nsp[0];
    #pragma unroll
    for (int m = 0; m < 8; ++m) {
      int o = wr * 128 + m * 16 + lq * 4;
      #pragma unroll
      for (int n = 0; n < 4; ++n) {
        int pix = pix0 + wc * 64 + n * 16 + lr;
        int p = pix >> 7, q = pix & 127;
        float nz = ns * noise[((size_t)b << 14) + (p << 7) + q];
        #pragma unroll
        for (int r = 0; r < 4; ++r) {
          float v = acc[m][n][r] + nz + bias[o + r];
          v = (v >= 0.f ? v : LEAKF * v) * SQRT2C;
          __builtin_nontemporal_store(v, &Yf[(((size_t)b * 256 + o + r) << 14) + (p << 7) + q]);
        }
      }
    }
  } else {
    // OM==3: A[b][kx][p=2gy+rp][gx][o] bf16, rho = rp*3+kx — NONTEMPORAL (streaming, read-once)
    int rp = rho / 3, kx = rho % 3;
    #pragma unroll
    for (int m = 0; m < 8; ++m) {
      int o = wr * 128 + m * 16 + lq * 4;
      #pragma unroll
      for (int n = 0; n < 4; ++n) {
        int pix = pix0 + wc * 64 + n * 16 + lr;
        int p2 = ((pix >> 6) << 1) + rp, gxp = pix & 63;
        u32x2 pk;
        pk[0] = (unsigned)f2bf(acc[m][n][0]) | ((unsigned)f2bf(acc[m][n][1]) << 16);
        pk[1] = (unsigned)f2bf(acc[m][n][2]) | ((unsigned)f2bf(acc[m][n][3]) << 16);
        __builtin_nontemporal_store(pk,
            (u32x2*)&Yb[((((size_t)(b * 3) + kx) * 128 + p2) * 64 + gxp) * 256 + o]);
      }
    }
  }
}

// ---------------- horizontal mix + epilogue: y1p interior (A read nontemporally) ----------------
__global__ void k_hmix(const unsigned short* __restrict__ A, const float* __restrict__ noise,
                       const float* __restrict__ nsp, const float* __restrict__ bias,
                       unsigned short* __restrict__ y1p) {
  int bid = blockIdx.x;                  // 16384 = b(8)*p(128)*qg(16)
  int qg = bid & 15;
  int p = (bid >> 4) & 127;
  int b = bid >> 11;
  int o0 = (threadIdx.x & 31) * 8;
  int q = qg * 8 + (threadIdx.x >> 5);
  int gq = q >> 1;
  float rqf = (float)(q & 1);
  float acc[8];
  #pragma unroll
  for (int r = 0; r < 8; ++r) acc[r] = 0.f;
  #pragma unroll
  for (int v = 0; v < 3; ++v) {
    int gxx = gq + v - 1;
    float bmask = (gxx >= 0 && gxx <= 63) ? 1.f : 0.f;
    int gxc = gxx < 0 ? 0 : (gxx > 63 ? 63 : gxx);
    #pragma unroll
    for (int kx = 0; kx < 3; ++kx) {
      float C0 = B1v(4 - 2 * v - kx);
      float C1 = B1v(5 - 2 * v - kx);
      if (C0 == 0.f && C1 == 0.f) continue;            // folds at compile time
      float coef = (C0 + (C1 - C0) * rqf) * bmask;
      u32x4 av = __builtin_nontemporal_load(
          (const u32x4*)&A[(((size_t)(b * 3 + kx) * 128 + p) * 64 + gxc) * 256 + o0]);
      acc[0] += coef * bflo(av[0]); acc[1] += coef * bfhi(av[0]);
      acc[2] += coef * bflo(av[1]); acc[3] += coef * bfhi(av[1]);
      acc[4] += coef * bflo(av[2]); acc[5] += coef * bfhi(av[2]);
      acc[6] += coef * bflo(av[3]); acc[7] += coef * bfhi(av[3]);
    }
  }
  float ns = nsp[0];
  float nz = ns * noise[((size_t)b << 14) + (p << 7) + q];
  float4 bl = *(const float4*)&bias[o0];
  float4 bh = *(const float4*)&bias[o0 + 4];
  float bb[8] = {bl.x, bl.y, bl.z, bl.w, bh.x, bh.y, bh.z, bh.w};
  unsigned short ov[8];
  #pragma unroll
  for (int r = 0; r < 8; ++r) {
    float vv = acc[r] * 0.0625f + nz + bb[r];
    vv = (vv >= 0.f ? vv : LEAKF * vv) * SQRT2C;
    ov[r] = f2bf(vv);
  }
  uint4 pk;
  pk.x = (unsigned)ov[0] | ((unsigned)ov[1] << 16);
  pk.y = (unsigned)ov[2] | ((unsigned)ov[3] << 16);
  pk.z = (unsigned)ov[4] | ((unsigned)ov[5] << 16);
  pk.w = (unsigned)ov[6] | ((unsigned)ov[7] << 16);
  *(uint4*)&y1p[(((size_t)(b * 130) + p + 1) * 130 + q + 1) * 256 + o0] = pk;
}

extern "C" void kernel_launch(void* const* d_in, const int* in_sizes, int n_in,
                              void* d_out, int out_size, void* d_ws, size_t ws_size,
                              hipStream_t stream) {
  (void)in_sizes; (void)n_in; (void)out_size; (void)ws_size;
  const float* x       = (const float*)d_in[0];
  const float* w1      = (const float*)d_in[1];
  const float* w2      = (const float*)d_in[2];
  const float* noise1  = (const float*)d_in[3];
  const float* noise2  = (const float*)d_in[4];
  const float* weight1 = (const float*)d_in[5];
  const float* aff1w   = (const float*)d_in[6];
  const float* aff1b   = (const float*)d_in[7];
  const float* weight2 = (const float*)d_in[8];
  const float* aff2w   = (const float*)d_in[9];
  const float* aff2b   = (const float*)d_in[10];
  const float* ns1     = (const float*)d_in[11];
  const float* ns2     = (const float*)d_in[12];
  const float* b1      = (const float*)d_in[13];
  const float* b2      = (const float*)d_in[14];

  // Workspace map (proven-safe bound: <= 189,882,368 B):
  //   header           0 ..      40,960
  //   xt_v        40,960 ..  34,643,968   (8*66*64*512 bf16)
  //   Wv      34,643,968 ..  72,392,704   (8*6*3*256*512 bf16)
  //   W2m     72,392,704 ..  81,829,888
  //   A       81,829,888 .. 182,493,184   (8*3*128*64*256 bf16 = 100,663,296)
  //   y1p         40,960 ..  69,263,360   (aliases xt_v+Wv, both dead before hmix)
  char* ws = (char*)d_ws;
  float* s1 = (float*)(ws + 0);
  float* s2 = (float*)(ws + 16384);
  float* d1 = (float*)(ws + 24576);
  float* d2 = (float*)(ws + 32768);
  unsigned short* xt   = (unsigned short*)(ws + 40960);
  unsigned short* Wv   = (unsigned short*)(ws + 34643968);
  unsigned short* W2m  = (unsigned short*)(ws + 72392704);
  unsigned short* A    = (unsigned short*)(ws + 81829888);
  unsigned short* y1p  = (unsigned short*)(ws + 40960);

  (void)hipFuncSetAttribute((const void*)k_conv8<512, 6, 66, 6, 3, 18, 3>,
                            hipFuncAttributeMaxDynamicSharedMemorySize, 131072);
  (void)hipFuncSetAttribute((const void*)k_conv8<256, 7, 130, 1, 9, 9, 2>,
                            hipFuncAttributeMaxDynamicSharedMemorySize, 131072);

  k_affine<<<1024, 256, 0, stream>>>(w1, aff1w, aff1b, s1, 512);
  k_affine<<<512,  256, 0, stream>>>(w2, aff2w, aff2b, s2, 256);
  k_demod<<<2048, 256, 0, stream>>>(weight1, s1, d1, 512);
  k_demod<<<2048, 256, 0, stream>>>(weight2, s2, d2, 256);
  k_wvert<<<4096, 256, 0, stream>>>(weight1, s1, d1, Wv);
  k_weff2<<<2048, 256, 0, stream>>>(weight2, s2, d2, W2m);
  k_fillv<<<256, 256, 0, stream>>>(xt);
  k_txpose<<<8192, 256, 0, stream>>>(x, xt);

  // A-GEMM: vertical taps folded into weights; 6 panels (rp,kx) per b, K=1536.
  k_conv8<512, 6, 66, 6, 3, 18, 3><<<768, 512, 131072, stream>>>(
      xt, Wv, nullptr, nullptr, nullptr, A, nullptr);

  k_border_y1<<<516, 256, 0, stream>>>(y1p);
  k_hmix<<<16384, 256, 0, stream>>>(A, noise1, ns1, b1, y1p);
  k_conv8<256, 7, 130, 1, 9, 9, 2><<<512, 512, 131072, stream>>>(
      y1p, W2m, noise2, ns2, b2, nullptr, (float*)d_out);
}

// Round 13
// 399.485 us; speedup vs baseline: 1.1963x; 1.1962x over previous
//
#include <hip/hip_runtime.h>
#include <hip/hip_bf16.h>

#define SQRT2C 1.41421356237309515f
#define LEAKF 0.2f

typedef __attribute__((ext_vector_type(4))) float f32x4;
typedef __attribute__((ext_vector_type(8))) __bf16 bf16x8;
typedef unsigned int u32x4 __attribute__((ext_vector_type(4)));

#define GLOAD16(g, l) \
  __builtin_amdgcn_global_load_lds((const __attribute__((address_space(1))) void*)(const void*)(g), \
                                   (__attribute__((address_space(3))) void*)(void*)(l), 16, 0, 0)

__device__ __forceinline__ unsigned short f2bf(float f) {
  unsigned int u = __float_as_uint(f);
  unsigned int r = (u + 0x7fffu + ((u >> 16) & 1u)) >> 16;
  return (unsigned short)r;
}
__device__ __forceinline__ float bflo(unsigned int w) { return __uint_as_float(w << 16); }
__device__ __forceinline__ float bfhi(unsigned int w) { return __uint_as_float(w & 0xffff0000u); }

// blur 1-D factor: B1 = [1,3,3,1], zero outside.  Tm[rp][u][k] == B1v(4-2u-k+rp)  (verified r1-3)
constexpr float B1v(int c) { return (c < 0 || c > 3) ? 0.f : ((c == 0 || c == 3) ? 1.f : 3.f); }

// ---------------- s = w @ aff_w.T + aff_b + 1 ----------------
__global__ void k_affine(const float* __restrict__ w, const float* __restrict__ aw,
                         const float* __restrict__ ab, float* __restrict__ s, int C) {
  int wid = (blockIdx.x * blockDim.x + threadIdx.x) >> 6;
  int lane = threadIdx.x & 63;
  int b = wid / C, i = wid % C;
  const float* wr = w + (size_t)b * 512;
  const float* ar = aw + (size_t)i * 512;
  float acc = 0.f;
  #pragma unroll
  for (int l = 0; l < 512; l += 64) acc += wr[l + lane] * ar[l + lane];
  #pragma unroll
  for (int off = 32; off; off >>= 1) acc += __shfl_down(acc, off, 64);
  if (lane == 0) s[wid] = acc + ab[i] + 1.0f;
}

// ---------------- d[b,o] = rsqrt(sum_i s^2 * sum_tap w^2 + 1e-8) ----------------
__global__ void k_demod(const float* __restrict__ weight, const float* __restrict__ s,
                        float* __restrict__ d, int CIN) {
  int o = blockIdx.x & 255, b = blockIdx.x >> 8;
  int t = threadIdx.x;
  const float* wr = weight + (size_t)o * CIN * 9;
  const float* sr = s + (size_t)b * CIN;
  float acc = 0.f;
  for (int i = t; i < CIN; i += 256) {
    float sv = sr[i];
    float ws = 0.f;
    #pragma unroll
    for (int k = 0; k < 9; ++k) { float w = wr[(size_t)i * 9 + k]; ws += w * w; }
    acc += sv * sv * ws;
  }
  __shared__ float red[256];
  red[t] = acc; __syncthreads();
  for (int h = 128; h; h >>= 1) { if (t < h) red[t] += red[t + h]; __syncthreads(); }
  if (t == 0) d[blockIdx.x] = rsqrtf(red[0] + 1e-8f);
}

// ---- Wv[b][rp*3+kx][u][o][i] = sum_ky Tm[rp][u][ky] * wm1[ky][kx][o][i]  (vertical mix in weights)
__global__ void k_wvert(const float* __restrict__ w1, const float* __restrict__ s1,
                        const float* __restrict__ d1, unsigned short* __restrict__ Wv) {
  int t = blockIdx.x * 256 + threadIdx.x;   // 8*256*512 threads
  int i = t & 511, o = (t >> 9) & 255, b = t >> 17;
  float sd = s1[b * 512 + i] * d1[b * 256 + o];
  const float* wp = w1 + ((size_t)o * 512 + i) * 9;
  float wm[3][3];
  #pragma unroll
  for (int ky = 0; ky < 3; ++ky)
    #pragma unroll
    for (int kx = 0; kx < 3; ++kx) wm[ky][kx] = wp[ky * 3 + kx] * sd;
  #pragma unroll
  for (int rp = 0; rp < 2; ++rp)
    #pragma unroll
    for (int u = 0; u < 3; ++u)
      #pragma unroll
      for (int kx = 0; kx < 3; ++kx) {
        float v = 0.f;
        #pragma unroll
        for (int ky = 0; ky < 3; ++ky) v += B1v(4 - 2 * u - ky + rp) * wm[ky][kx];
        Wv[(((size_t)(b * 6 + rp * 3 + kx)) * 3 + u) * 131072 + (size_t)o * 512 + i] = f2bf(v);
      }
}

// ---------------- W2m[b][tap][o][i] (bf16) ----------------
__global__ void k_weff2(const float* __restrict__ w2, const float* __restrict__ s2,
                        const float* __restrict__ d2, unsigned short* __restrict__ Wm) {
  int t = blockIdx.x * 256 + threadIdx.x;   // 8*256*256 threads
  int i = t & 255, o = (t >> 8) & 255, b = t >> 16;
  float sd = s2[b * 256 + i] * d2[b * 256 + o];
  const float* wp = w2 + ((size_t)o * 256 + i) * 9;
  #pragma unroll
  for (int k = 0; k < 9; ++k)
    Wm[((size_t)(b * 9 + k) * 256 + o) * 256 + i] = f2bf(wp[k] * sd);
}

// ---------------- border-only zero fill for y1p halo ----------------
__global__ void k_border_y1(unsigned short* __restrict__ y1p) {
  int t = blockIdx.x * 256 + threadIdx.x;   // 8*516*32 threads, 1 uint4 each
  int l = t & 31;
  int c = (t >> 5) % 516;
  int b = (t >> 5) / 516;
  int p_, q_;
  if (c < 130)      { p_ = 0;       q_ = c; }
  else if (c < 260) { p_ = 129;     q_ = c - 130; }
  else if (c < 388) { p_ = c - 259; q_ = 0; }
  else              { p_ = c - 387; q_ = 129; }
  uint4* p = (uint4*)(y1p + (((size_t)(b * 130) + p_) * 130 + q_) * 256);
  p[l] = make_uint4(0u, 0u, 0u, 0u);
}

// ---------------- zero rows 0 and 65 of xt_v [8][66][64][512] ----------------
__global__ void k_fillv(unsigned short* __restrict__ xt) {
  int t = blockIdx.x * 256 + threadIdx.x;   // 65536 uint4
  int j = t & 4095;
  int r = (t >> 12) & 1;
  int b = t >> 13;
  uint4* p = (uint4*)(xt + ((size_t)(b * 66) + (r ? 65 : 0)) * 64 * 512);
  p[j] = make_uint4(0u, 0u, 0u, 0u);
}

// ---- x [8][512][64][64] f32 -> xt_v [8][66][64][512] bf16 (rows 1..64 = x rows 0..63) ----
__global__ void k_txpose(const float* __restrict__ x, unsigned short* __restrict__ xt) {
  int bid = blockIdx.x;            // 8192 = b(8) * y(64) * x0(2) * i0(8)
  int i0 = (bid & 7) * 64;
  int x0 = ((bid >> 3) & 1) * 32;
  int y  = (bid >> 4) & 63;
  int b  = bid >> 10;
  int tx = threadIdx.x & 31, ty = threadIdx.x >> 5;
  __shared__ float tile[64][33];
  const float* xp = x + ((size_t)(b * 512 + i0) * 64 + y) * 64 + x0;
  for (int ii = ty; ii < 64; ii += 8) tile[ii][tx] = xp[(size_t)ii * 4096 + tx];
  __syncthreads();
  unsigned short* op = xt + (((size_t)(b * 66) + y + 1) * 64 + x0) * 512 + i0;
  for (int xx = ty; xx < 32; xx += 8) {
    int iL = tx * 2;
    unsigned int pk = (unsigned int)f2bf(tile[iL][xx]) | ((unsigned int)f2bf(tile[iL + 1][xx]) << 16);
    *(unsigned int*)&op[(size_t)xx * 512 + iL] = pk;
  }
}

// ================= 256x256 tile, 8-wave, BK=64, 2-buffer, 8-PHASE schedule (m201 port) =========
// Per iteration: 2 K-tiles, 8 phases. Each phase: {ds_read quadrant frags || stage one 16KB unit}
// -> barrier -> lgkmcnt(0) -> setprio(1) 16 MFMA setprio(0) -> [vmcnt at ph3/ph7] -> barrier.
// LDS: 2 x (A 256x64 + B 256x64) bf16 = 128 KiB, flat rows (128 B) with kb ^= (row&7)<<4 swizzle;
// staging pre-applies the inverse permutation on the per-lane GLOBAL k-offset.
// Unit overwrite schedule derived so every unit has >=1 barrier after its last reader.
template<int CIN, int GSH, int HP, int RHO_N, int TAPS, int PANB, int OM>
__global__ __launch_bounds__(512, 2) void k_gemm8p(
    const unsigned short* __restrict__ Xt,
    const unsigned short* __restrict__ Wt,
    const float* __restrict__ noise,
    const float* __restrict__ nsp,
    const float* __restrict__ bias,
    unsigned short* __restrict__ Yb,
    float* __restrict__ Yf)
{
  constexpr int GRID = 1 << GSH;
  constexpr int NT = (GRID * GRID) / 256;
  constexpr int NKT = TAPS * (CIN / 64);   // K-tiles of 64
  constexpr int NIT = NKT / 2;             // 2 K-tiles per iteration (even: 24->12, 36->18)
  constexpr int KSH = (CIN == 512) ? 3 : 2;
  constexpr int KMASK = (CIN / 64) - 1;
  constexpr int TOT = NT * RHO_N * 8;
  extern __shared__ char smem[];

  int bid0 = blockIdx.x;
  int bid = (bid0 & 7) * (TOT / 8) + (bid0 >> 3);   // XCD-chunked, bijective (TOT%8==0)
  int nt = bid % NT;
  int rho = (bid / NT) % RHO_N;
  int b = bid / (NT * RHO_N);
  int pix0 = nt * 256;
  int tid = threadIdx.x, lane = tid & 63, w = tid >> 6;
  int lr = lane & 15, lq = lane >> 4;
  int wr = w >> 2, wc = w & 3;
  int lhi = lane >> 3, llo = lane & 7;
  int ksrc = ((llo ^ lhi) << 3);            // inverse-swizzled per-lane k element offset

  const unsigned short* Wp = Wt + ((size_t)b * PANB + rho * TAPS) * 256 * CIN;
  size_t aOff = (size_t)(w * 8 + lhi) * CIN + ksrc;
  size_t bOff = (size_t)lhi * CIN + ksrc;
  const unsigned short* XtB;
  if constexpr (OM == 3) XtB = Xt + (size_t)b * HP * 64 * CIN;                 // pixel-linear
  else                   XtB = Xt + ((size_t)(b * HP + (pix0 >> 7))) * 130 * CIN;

  // ---- staging: one unit = 128 rows x 128 B = 16 KB = 2 gload_lds/thread ----
  auto stageA = [&](int buf, int t, int u) {
    int tap = t >> KSH; size_t ke = (size_t)((t & KMASK) << 6);
    const unsigned short* s = Wp + (size_t)tap * 256 * CIN + ke + (size_t)u * 64 * CIN + aOff;
    char* d = smem + buf * 65536 + u * 8192 + w * 1024;
    GLOAD16(s, d);                                   // rows [u*64, u*64+64) block j=0
    GLOAD16(s + (size_t)128 * CIN, d + 16384);       // rows +128 (j=1)
  };
  auto stageB = [&](int buf, int t, int u) {
    int tap = t >> KSH; size_t ke = (size_t)((t & KMASK) << 6);
    size_t tk;
    if constexpr (OM == 3) tk = (size_t)tap * 64 * CIN + ke;
    else                   tk = ((size_t)(tap / 3) * HP + (tap % 3)) * CIN + ke;
    int c0 = w >> 2, r0 = (w & 3) * 8;
    int rowA = c0 * 64 + u * 32 + r0;
    int rowB = rowA + 128;
    char* db = smem + buf * 65536 + 32768;
    size_t sA, sB;
    if constexpr (OM == 3) { sA = (size_t)(pix0 + rowA) * CIN; sB = (size_t)(pix0 + rowB) * CIN; }
    else { sA = ((size_t)(rowA >> 7) * 130 + (rowA & 127)) * CIN;
           sB = ((size_t)(rowB >> 7) * 130 + (rowB & 127)) * CIN; }
    GLOAD16(XtB + sA + tk + bOff, db + rowA * 128);
    GLOAD16(XtB + sB + tk + bOff, db + rowB * 128);
  };

  // ---- fragment reads (swizzled) ----
  int ldsA = (wr * 128 + lr) * 128;
  int ldsB = 32768 + (wc * 64 + lr) * 128;
  int xk[2] = { (lq * 16) ^ ((lr & 7) << 4), (64 + lq * 16) ^ ((lr & 7) << 4) };

  f32x4 acc[8][4];
  #pragma unroll
  for (int m = 0; m < 8; ++m)
    #pragma unroll
    for (int n = 0; n < 4; ++n) acc[m][n] = (f32x4){0.f, 0.f, 0.f, 0.f};

  bf16x8 af[2][4], bv[2][4];
  auto readA = [&](const char* base, int mq) {
    #pragma unroll
    for (int kk = 0; kk < 2; ++kk)
      #pragma unroll
      for (int m = 0; m < 4; ++m)
        af[kk][m] = *(const bf16x8*)(base + ldsA + (mq * 4 + m) * 2048 + xk[kk]);
  };
  auto readB = [&](const char* base, int nq) {
    #pragma unroll
    for (int kk = 0; kk < 2; ++kk)
      #pragma unroll
      for (int n = 0; n < 2; ++n)
        bv[kk][nq * 2 + n] = *(const bf16x8*)(base + ldsB + (nq * 2 + n) * 2048 + xk[kk]);
  };
  auto mma = [&](int mq, int nq) {
    __builtin_amdgcn_s_setprio(1);
    #pragma unroll
    for (int kk = 0; kk < 2; ++kk)
      #pragma unroll
      for (int m = 0; m < 4; ++m)
        #pragma unroll
        for (int n = 0; n < 2; ++n)
          acc[mq * 4 + m][nq * 2 + n] = __builtin_amdgcn_mfma_f32_16x16x32_bf16(
              af[kk][m], bv[kk][nq * 2 + n], acc[mq * 4 + m][nq * 2 + n], 0, 0, 0);
    __builtin_amdgcn_s_setprio(0);
  };

#define PH_SYNC()  __builtin_amdgcn_s_barrier(); \
                   asm volatile("s_waitcnt lgkmcnt(0)" ::: "memory")
#define PH_END()   __builtin_amdgcn_s_barrier()

  // ---- prologue: tile0 all 4 units + tile1 A0,B0 (12 loads); retire tile0, keep tile1 ----
  stageA(0, 0, 0); stageB(0, 0, 0); stageA(0, 0, 1); stageB(0, 0, 1);
  stageA(1, 1, 0); stageB(1, 1, 0);
  asm volatile("s_waitcnt vmcnt(4)" ::: "memory");
  __builtin_amdgcn_s_barrier();

  const char* B0 = smem;
  const char* B1 = smem + 65536;

  #pragma unroll 1
  for (int i = 0; i < NIT; ++i) {
    int a = 2 * i;
    bool nl = (i + 1 < NIT);
    // ph0: tile a, quad(0,0); stage buf1 <- tile a+1 A-unit1
    readA(B0, 0); readB(B0, 0);
    stageA(1, a + 1, 1);
    PH_SYNC(); mma(0, 0); PH_END();
    // ph1: quad(0,1); stage buf1 <- a+1 B-unit1
    readB(B0, 1);
    stageB(1, a + 1, 1);
    PH_SYNC(); mma(0, 1); PH_END();
    // ph2: quad(1,0); stage buf0 <- a+2 A-unit0 (A-unit0 retired after ph1)
    readA(B0, 1);
    if (nl) stageA(0, a + 2, 0);
    PH_SYNC(); mma(1, 0); PH_END();
    // ph3: quad(1,1); stage buf0 <- a+2 B-unit0 (retired after ph2); vmcnt gates buf1 for ph4-7
    if (nl) stageB(0, a + 2, 0);
    PH_SYNC(); mma(1, 1);
    if (nl) { asm volatile("s_waitcnt vmcnt(4)" ::: "memory"); }
    else    { asm volatile("s_waitcnt vmcnt(0)" ::: "memory"); }
    PH_END();
    // ph4: tile a+1, quad(0,0); stage buf0 <- a+2 A-unit1 (retired after ph3)
    readA(B1, 0); readB(B1, 0);
    if (nl) stageA(0, a + 2, 1);
    PH_SYNC(); mma(0, 0); PH_END();
    // ph5: quad(0,1); stage buf0 <- a+2 B-unit1
    readB(B1, 1);
    if (nl) stageB(0, a + 2, 1);
    PH_SYNC(); mma(0, 1); PH_END();
    // ph6: quad(1,0); stage buf1 <- a+3 A-unit0 (buf1 A-unit0 retired after ph5)
    readA(B1, 1);
    if (nl) stageA(1, a + 3, 0);
    PH_SYNC(); mma(1, 0); PH_END();
    // ph7: quad(1,1); stage buf1 <- a+3 B-unit0 (retired after ph6); vmcnt gates buf0 for next iter
    if (nl) stageB(1, a + 3, 0);
    PH_SYNC(); mma(1, 1);
    if (nl) { asm volatile("s_waitcnt vmcnt(4)" ::: "memory"); }
    PH_END();
  }
#undef PH_SYNC
#undef PH_END

  // ---- epilogue (identical to verified r9) ----
  if constexpr (OM == 2) {
    float ns = nsp[0];
    #pragma unroll
    for (int m = 0; m < 8; ++m) {
      int o = wr * 128 + m * 16 + lq * 4;
      #pragma unroll
      for (int n = 0; n < 4; ++n) {
        int pix = pix0 + wc * 64 + n * 16 + lr;
        int p = pix >> 7, q = pix & 127;
        float nz = ns * noise[((size_t)b << 14) + (p << 7) + q];
        #pragma unroll
        for (int r = 0; r < 4; ++r) {
          float v = acc[m][n][r] + nz + bias[o + r];
          v = (v >= 0.f ? v : LEAKF * v) * SQRT2C;
          __builtin_nontemporal_store(v, &Yf[(((size_t)b * 256 + o + r) << 14) + (p << 7) + q]);
        }
      }
    }
  } else {
    // OM==3: A[b][kx][p=2gy+rp][gx][o] bf16, rho = rp*3+kx
    int rp = rho / 3, kx = rho % 3;
    #pragma unroll
    for (int m = 0; m < 8; ++m) {
      int o = wr * 128 + m * 16 + lq * 4;
      #pragma unroll
      for (int n = 0; n < 4; ++n) {
        int pix = pix0 + wc * 64 + n * 16 + lr;
        int p2 = ((pix >> 6) << 1) + rp, gxp = pix & 63;
        ushort4 pk;
        #pragma unroll
        for (int r = 0; r < 4; ++r) ((unsigned short*)&pk)[r] = f2bf(acc[m][n][r]);
        *(ushort4*)&Yb[((((size_t)(b * 3) + kx) * 128 + p2) * 64 + gxp) * 256 + o] = pk;
      }
    }
  }
}

// ---------------- horizontal mix + epilogue: y1p interior (A read nontemporally) ----------------
__global__ void k_hmix(const unsigned short* __restrict__ A, const float* __restrict__ noise,
                       const float* __restrict__ nsp, const float* __restrict__ bias,
                       unsigned short* __restrict__ y1p) {
  int bid = blockIdx.x;                  // 16384 = b(8)*p(128)*qg(16)
  int qg = bid & 15;
  int p = (bid >> 4) & 127;
  int b = bid >> 11;
  int o0 = (threadIdx.x & 31) * 8;
  int q = qg * 8 + (threadIdx.x >> 5);
  int gq = q >> 1;
  float rqf = (float)(q & 1);
  float acc[8];
  #pragma unroll
  for (int r = 0; r < 8; ++r) acc[r] = 0.f;
  #pragma unroll
  for (int v = 0; v < 3; ++v) {
    int gxx = gq + v - 1;
    float bmask = (gxx >= 0 && gxx <= 63) ? 1.f : 0.f;
    int gxc = gxx < 0 ? 0 : (gxx > 63 ? 63 : gxx);
    #pragma unroll
    for (int kx = 0; kx < 3; ++kx) {
      float C0 = B1v(4 - 2 * v - kx);
      float C1 = B1v(5 - 2 * v - kx);
      if (C0 == 0.f && C1 == 0.f) continue;            // folds at compile time
      float coef = (C0 + (C1 - C0) * rqf) * bmask;
      u32x4 av = __builtin_nontemporal_load(
          (const u32x4*)&A[(((size_t)(b * 3 + kx) * 128 + p) * 64 + gxc) * 256 + o0]);
      acc[0] += coef * bflo(av[0]); acc[1] += coef * bfhi(av[0]);
      acc[2] += coef * bflo(av[1]); acc[3] += coef * bfhi(av[1]);
      acc[4] += coef * bflo(av[2]); acc[5] += coef * bfhi(av[2]);
      acc[6] += coef * bflo(av[3]); acc[7] += coef * bfhi(av[3]);
    }
  }
  float ns = nsp[0];
  float nz = ns * noise[((size_t)b << 14) + (p << 7) + q];
  float4 bl = *(const float4*)&bias[o0];
  float4 bh = *(const float4*)&bias[o0 + 4];
  float bb[8] = {bl.x, bl.y, bl.z, bl.w, bh.x, bh.y, bh.z, bh.w};
  unsigned short ov[8];
  #pragma unroll
  for (int r = 0; r < 8; ++r) {
    float vv = acc[r] * 0.0625f + nz + bb[r];
    vv = (vv >= 0.f ? vv : LEAKF * vv) * SQRT2C;
    ov[r] = f2bf(vv);
  }
  uint4 pk;
  pk.x = (unsigned)ov[0] | ((unsigned)ov[1] << 16);
  pk.y = (unsigned)ov[2] | ((unsigned)ov[3] << 16);
  pk.z = (unsigned)ov[4] | ((unsigned)ov[5] << 16);
  pk.w = (unsigned)ov[6] | ((unsigned)ov[7] << 16);
  *(uint4*)&y1p[(((size_t)(b * 130) + p + 1) * 130 + q + 1) * 256 + o0] = pk;
}

extern "C" void kernel_launch(void* const* d_in, const int* in_sizes, int n_in,
                              void* d_out, int out_size, void* d_ws, size_t ws_size,
                              hipStream_t stream) {
  (void)in_sizes; (void)n_in; (void)out_size; (void)ws_size;
  const float* x       = (const float*)d_in[0];
  const float* w1      = (const float*)d_in[1];
  const float* w2      = (const float*)d_in[2];
  const float* noise1  = (const float*)d_in[3];
  const float* noise2  = (const float*)d_in[4];
  const float* weight1 = (const float*)d_in[5];
  const float* aff1w   = (const float*)d_in[6];
  const float* aff1b   = (const float*)d_in[7];
  const float* weight2 = (const float*)d_in[8];
  const float* aff2w   = (const float*)d_in[9];
  const float* aff2b   = (const float*)d_in[10];
  const float* ns1     = (const float*)d_in[11];
  const float* ns2     = (const float*)d_in[12];
  const float* b1      = (const float*)d_in[13];
  const float* b2      = (const float*)d_in[14];

  // Workspace map (proven-safe bound: <= 189,882,368 B):
  //   header           0 ..      40,960
  //   xt_v        40,960 ..  34,643,968   (8*66*64*512 bf16)
  //   Wv      34,643,968 ..  72,392,704   (8*6*3*256*512 bf16)
  //   W2m     72,392,704 ..  81,829,888
  //   A       81,829,888 .. 182,493,184   (8*3*128*64*256 bf16 = 100,663,296)
  //   y1p         40,960 ..  69,263,360   (aliases xt_v+Wv, both dead before hmix)
  char* ws = (char*)d_ws;
  float* s1 = (float*)(ws + 0);
  float* s2 = (float*)(ws + 16384);
  float* d1 = (float*)(ws + 24576);
  float* d2 = (float*)(ws + 32768);
  unsigned short* xt   = (unsigned short*)(ws + 40960);
  unsigned short* Wv   = (unsigned short*)(ws + 34643968);
  unsigned short* W2m  = (unsigned short*)(ws + 72392704);
  unsigned short* A    = (unsigned short*)(ws + 81829888);
  unsigned short* y1p  = (unsigned short*)(ws + 40960);

  (void)hipFuncSetAttribute((const void*)k_gemm8p<512, 6, 66, 6, 3, 18, 3>,
                            hipFuncAttributeMaxDynamicSharedMemorySize, 131072);
  (void)hipFuncSetAttribute((const void*)k_gemm8p<256, 7, 130, 1, 9, 9, 2>,
                            hipFuncAttributeMaxDynamicSharedMemorySize, 131072);

  k_affine<<<1024, 256, 0, stream>>>(w1, aff1w, aff1b, s1, 512);
  k_affine<<<512,  256, 0, stream>>>(w2, aff2w, aff2b, s2, 256);
  k_demod<<<2048, 256, 0, stream>>>(weight1, s1, d1, 512);
  k_demod<<<2048, 256, 0, stream>>>(weight2, s2, d2, 256);
  k_wvert<<<4096, 256, 0, stream>>>(weight1, s1, d1, Wv);
  k_weff2<<<2048, 256, 0, stream>>>(weight2, s2, d2, W2m);
  k_fillv<<<256, 256, 0, stream>>>(xt);
  k_txpose<<<8192, 256, 0, stream>>>(x, xt);

  // A-GEMM: vertical taps folded into weights; 6 panels (rp,kx) per b, K=1536; 768 = 3x256 blocks
  k_gemm8p<512, 6, 66, 6, 3, 18, 3><<<768, 512, 131072, stream>>>(
      xt, Wv, nullptr, nullptr, nullptr, A, nullptr);

  k_border_y1<<<516, 256, 0, stream>>>(y1p);
  k_hmix<<<16384, 256, 0, stream>>>(A, noise1, ns1, b1, y1p);
  // conv2: 3x3 on halo grid, K=2304; 512 = 2x256 blocks
  k_gemm8p<256, 7, 130, 1, 9, 9, 2><<<512, 512, 131072, stream>>>(
      y1p, W2m, noise2, ns2, b2, nullptr, (float*)d_out);
}